// Round 5
// baseline (5622.543 us; speedup 1.0000x reference)
//
#include <hip/hip_runtime.h>

namespace {
constexpr int kB = 16, kT = 512, kIN = 16, kD = 128, kH = 256, kL = 136, kO = 32;
constexpr int kSteps = kT - 1;      // 511
constexpr int NBLK = 256;           // block k: contraction tile d = k>>1, l-half = k&1
constexpr int NTHR = 512;
constexpr int LH   = 68;            // l per block
constexpr int NTILE = 5;            // 5 MFMA n-tiles (80 cols, 68 real)
// LDS layout (bytes) — uniform for all blocks
constexpr int OFF_W3L = 0;          // [5][8][2][64][8] bf16 (w,s,plane,lane,e) 81920
constexpr int OFF_AHI = 81920;      // [16][264] u16   8448
constexpr int OFF_ALO = 90368;      // [16][264] u16   8448
constexpr int OFF_DT  = 98816;      // [16][84]  f32   5376
constexpr int OFF_OMS = 104192;     // [16][68]  f32   4352
constexpr int OFF_Z1S = 108544;     // [256]     f32   1024
constexpr int OFF_HB  = 109568;     // [128]     f32    512
constexpr int OFF_HINC= 110080;     // [128]     f32    512
constexpr int OFF_RED = 110592;     // [16][8]   f32    512
constexpr size_t LDS_BYTES = 111104;
}

typedef __attribute__((ext_vector_type(8))) short short8;
typedef __attribute__((ext_vector_type(4))) float f32x4;

__device__ __forceinline__ float softplusf(float x) {
  return fmaxf(x, 0.0f) + log1pf(expf(-fabsf(x)));
}
__device__ __forceinline__ unsigned short f2bf(float x) {
  unsigned u = __float_as_uint(x);
  return (unsigned short)((u + 0x7FFFu + ((u >> 16) & 1u)) >> 16);
}
__device__ __forceinline__ float bf2f(unsigned short h) {
  return __uint_as_float(((unsigned)h) << 16);
}
#define ALOAD64(p)   __hip_atomic_load((p),  __ATOMIC_RELAXED, __HIP_MEMORY_SCOPE_AGENT)
#define ASTORE64(p,v) __hip_atomic_store((p), (v), __ATOMIC_RELAXED, __HIP_MEMORY_SCOPE_AGENT)

__global__ void __launch_bounds__(256)
rde_init(const float* __restrict__ x0,
         const float* __restrict__ iw1, const float* __restrict__ ib1,
         const float* __restrict__ iw2, const float* __restrict__ ib2,
         const float* __restrict__ iw3, const float* __restrict__ ib3,
         float* __restrict__ hist) {
  __shared__ float xs[kIN];
  __shared__ __align__(16) float t1[kH];
  __shared__ __align__(16) float t2[kH];
  const int b = blockIdx.x, tid = threadIdx.x;
  if (tid < kIN) xs[tid] = x0[b*kIN + tid];
  __syncthreads();
  {
    float a = ib1[tid];
#pragma unroll
    for (int i = 0; i < kIN; ++i) a = fmaf(xs[i], iw1[tid*kIN + i], a);
    t1[tid] = softplusf(a);
  }
  __syncthreads();
  {
    const float4* wr = (const float4*)(iw2 + (size_t)tid*kH);
    float a = ib2[tid];
#pragma unroll 8
    for (int q = 0; q < kH/4; ++q) {
      float4 w = wr[q];
      a = fmaf(t1[4*q+0], w.x, a); a = fmaf(t1[4*q+1], w.y, a);
      a = fmaf(t1[4*q+2], w.z, a); a = fmaf(t1[4*q+3], w.w, a);
    }
    t2[tid] = softplusf(a);
  }
  __syncthreads();
  if (tid < kD) {
    const float4* wr = (const float4*)(iw3 + (size_t)tid*kH);
    float a = ib3[tid];
#pragma unroll 8
    for (int q = 0; q < kH/4; ++q) {
      float4 w = wr[q];
      a = fmaf(t2[4*q+0], w.x, a); a = fmaf(t2[4*q+1], w.y, a);
      a = fmaf(t2[4*q+2], w.z, a); a = fmaf(t2[4*q+3], w.w, a);
    }
    hist[(size_t)b*kD + tid] = a;
  }
}

__global__ void __launch_bounds__(NTHR, 2)
rde_scan(const float* __restrict__ lsg,
         const float* __restrict__ fw1, const float* __restrict__ fb1,
         const float* __restrict__ fw2, const float* __restrict__ fb2,
         const float* __restrict__ fw3, const float* __restrict__ fb3,
         float* __restrict__ hist,
         unsigned long long* z2x, unsigned long long* partx) {
  extern __shared__ char smem[];
  unsigned short* W3L = (unsigned short*)(smem + OFF_W3L);
  unsigned short* Ahi = (unsigned short*)(smem + OFF_AHI);
  unsigned short* Alo = (unsigned short*)(smem + OFF_ALO);
  float* Dt   = (float*)(smem + OFF_DT);
  float* oms  = (float*)(smem + OFF_OMS);
  float* z1s  = (float*)(smem + OFF_Z1S);
  float* hb   = (float*)(smem + OFF_HB);
  float* hinc = (float*)(smem + OFF_HINC);
  float* red  = (float*)(smem + OFF_RED);

  const int tid  = threadIdx.x;
  const int k    = blockIdx.x;
  const int wave = tid >> 6, lane = tid & 63;
  const int d_own = k >> 1, l0 = (k & 1) * LH;
  const bool isMLP = (k < kB);
  const int b_own = k;                       // valid when isMLP
  const int j = tid >> 1, ksp = tid & 1;     // MLP dot assignment

  // ---------------- prologue ----------------
  // fw3 slice -> LDS in per-lane-consecutive MFMA-B fragment order
  for (int i = tid; i < NTILE*8*64; i += NTHR) {
    const int w = i >> 9, s = (i >> 6) & 7, ln = i & 63;
    const int nl = w*16 + (ln & 15), g = ln >> 4;
    unsigned hi4[4], lo4[4];
    if (nl < LH) {
      const float* wrow = fw3 + ((size_t)d_own*kL + l0 + nl)*kH + s*32 + g*8;
#pragma unroll
      for (int e = 0; e < 4; ++e) {
        float v0 = wrow[2*e], v1 = wrow[2*e+1];
        unsigned short h0 = f2bf(v0), h1 = f2bf(v1);
        unsigned short l0_ = f2bf(v0 - bf2f(h0)), l1_ = f2bf(v1 - bf2f(h1));
        hi4[e] = (unsigned)h0 | ((unsigned)h1 << 16);
        lo4[e] = (unsigned)l0_ | ((unsigned)l1_ << 16);
      }
    } else {
#pragma unroll
      for (int e = 0; e < 4; ++e) { hi4[e] = 0u; lo4[e] = 0u; }
    }
    unsigned* dh = (unsigned*)(W3L + (((w*8+s)*2+0)*64 + ln)*8);
    unsigned* dl = (unsigned*)(W3L + (((w*8+s)*2+1)*64 + ln)*8);
#pragma unroll
    for (int e = 0; e < 4; ++e) { dh[e] = hi4[e]; dl[e] = lo4[e]; }
  }
  float biasv = 0.f;
  if (wave < NTILE) {
    int nl = wave*16 + (lane & 15);
    if (nl < LH) biasv = fb3[(size_t)d_own*kL + l0 + nl];
  }
  // MLP weight slices -> VGPRs (192 regs/thread; batch-independent)
  float w1r[64], w2r[128];
  float myfb1 = 0.f, myfb2 = 0.f;
  if (isMLP) {
    const float* p1 = fw1 + (size_t)j*kD + ksp*64;
#pragma unroll
    for (int q = 0; q < 16; ++q) {
      float4 v = *(const float4*)(p1 + 4*q);
      w1r[4*q] = v.x; w1r[4*q+1] = v.y; w1r[4*q+2] = v.z; w1r[4*q+3] = v.w;
    }
    const float* p2 = fw2 + (size_t)j*kH + ksp*128;
#pragma unroll
    for (int q = 0; q < 32; ++q) {
      float4 v = *(const float4*)(p2 + 4*q);
      w2r[4*q] = v.x; w2r[4*q+1] = v.y; w2r[4*q+2] = v.z; w2r[4*q+3] = v.w;
    }
    myfb1 = fb1[j]; myfb2 = fb2[j];
    for (int i = tid; i < kD; i += NTHR) hb[i] = hist[(size_t)b_own*kD + i];
  }
  __syncthreads();

  // ---------------- scan ----------------
  for (int t = 0; t < kSteps; ++t) {
    const unsigned epw = (unsigned)(t + 1);

    if (isMLP) {
      // z1[j] = softplus(h . fw1[j]) — weights in VGPR, h broadcast from LDS
      {
        float a = 0.f;
#pragma unroll
        for (int q = 0; q < 16; ++q) {
          float4 h4 = *(const float4*)(hb + ksp*64 + 4*q);
          a = fmaf(h4.x, w1r[4*q  ], a); a = fmaf(h4.y, w1r[4*q+1], a);
          a = fmaf(h4.z, w1r[4*q+2], a); a = fmaf(h4.w, w1r[4*q+3], a);
        }
        a += __shfl_xor(a, 1);
        if (ksp == 0) z1s[j] = softplusf(a + myfb1);
      }
      __syncthreads();
      // z2[j] = softplus(z1 . fw2[j]); publish epoch-embedded packed bf16 hi/lo
      {
        float c = 0.f;
#pragma unroll
        for (int q = 0; q < 32; ++q) {
          float4 z4 = *(const float4*)(z1s + ksp*128 + 4*q);
          c = fmaf(z4.x, w2r[4*q  ], c); c = fmaf(z4.y, w2r[4*q+1], c);
          c = fmaf(z4.z, w2r[4*q+2], c); c = fmaf(z4.w, w2r[4*q+3], c);
        }
        c += __shfl_xor(c, 1);
        if (ksp == 0) {
          float v = softplusf(c + myfb2);
          unsigned short hh = f2bf(v), ll = f2bf(v - bf2f(hh));
          unsigned long long pk = (unsigned long long)((unsigned)hh | ((unsigned)ll << 16))
                                | ((unsigned long long)epw << 32);
          ASTORE64(z2x + b_own*kH + j, pk);
        }
      }
    }

    // lsg slice -> oms (tid>=256; overlaps the z2 poll below)
    if (tid >= 256) {
      int c = tid - 256;
#pragma unroll 2
      for (int rep = 0; rep < 2; ++rep) {
        int cc = c + rep*256;
        if (cc < 272) {
          int bb = cc / 17, ii = cc % 17;
          float4 v = *(const float4*)(lsg + ((size_t)bb*kSteps + t)*kL + l0 + ii*4);
          *(float4*)(oms + bb*LH + ii*4) = v;
        }
      }
    }

    // all blocks: batched epoch-embedded z2 poll (8 u64 per thread, one RTT/round)
    {
      const unsigned long long* src = z2x + tid*8;
      unsigned long long q8[8];
      for (;;) {
        bool ok = true;
#pragma unroll
        for (int i = 0; i < 8; ++i) q8[i] = ALOAD64(src + i);
#pragma unroll
        for (int i = 0; i < 8; ++i) ok &= ((unsigned)(q8[i] >> 32) == epw);
        if (ok) break;
        __builtin_amdgcn_s_sleep(1);
      }
      const int e0 = tid*8, m = e0 >> 8, kk = e0 & 255;
      unsigned short* ph = Ahi + m*264 + kk;
      unsigned short* pl = Alo + m*264 + kk;
#pragma unroll
      for (int i = 0; i < 4; ++i) {
        unsigned a = (unsigned)q8[2*i], b = (unsigned)q8[2*i+1];
        *(unsigned*)(ph + 2*i) = (a & 0xffffu) | (b << 16);
        *(unsigned*)(pl + 2*i) = (a >> 16) | (b & 0xffff0000u);
      }
    }
    __syncthreads();

    // MFMA: waves 0-4, B-fragments from LDS (lane-consecutive, conflict-free)
    if (wave < NTILE) {
      f32x4 acc = {biasv, biasv, biasv, biasv};
      const int l15 = lane & 15, g = lane >> 4;
      const unsigned short* arh = Ahi + l15*264;
      const unsigned short* arl = Alo + l15*264;
#pragma unroll
      for (int s = 0; s < 8; ++s) {
        short8 ah = *(const short8*)(arh + s*32 + g*8);
        short8 al = *(const short8*)(arl + s*32 + g*8);
        short8 bh = *(const short8*)(W3L + ((wave*16 + s*2 + 0)*64 + lane)*8);
        short8 bl = *(const short8*)(W3L + ((wave*16 + s*2 + 1)*64 + lane)*8);
        acc = __builtin_amdgcn_mfma_f32_16x16x32_bf16(ah, bh, acc, 0, 0, 0);
        acc = __builtin_amdgcn_mfma_f32_16x16x32_bf16(ah, bl, acc, 0, 0, 0);
        acc = __builtin_amdgcn_mfma_f32_16x16x32_bf16(al, bh, acc, 0, 0, 0);
      }
#pragma unroll
      for (int r = 0; r < 4; ++r)
        Dt[(g*4 + r)*84 + wave*16 + l15] = acc[r];
    }
    __syncthreads();

    // contraction: tanh * logsig, reduce over l
    {
      const int b3 = tid & 15, lb = tid >> 4;   // lb 0..31
      float p = tanhf(Dt[b3*84 + lb     ]) * oms[b3*LH + lb     ]
              + tanhf(Dt[b3*84 + lb + 32]) * oms[b3*LH + lb + 32];
      if (lb < 4)
        p += tanhf(Dt[b3*84 + lb + 64]) * oms[b3*LH + lb + 64];
      p += __shfl_xor(p, 16); p += __shfl_xor(p, 32);
      if (lane < 16) red[lane*8 + wave] = p;
    }
    __syncthreads();
    if (tid < 16) {
      float s = 0.f;
#pragma unroll
      for (int jw = 0; jw < 8; ++jw) s += red[tid*8 + jw];
      unsigned long long pk = (unsigned long long)__float_as_uint(s)
                            | ((unsigned long long)epw << 32);
      ASTORE64(partx + tid*NBLK + k, pk);      // partx[b][k]
    }

    // MLP blocks: poll all 256 partials for own b, update h
    if (isMLP) {
      if (tid < 256) {
        const unsigned long long* pp = partx + b_own*NBLK + tid;
        unsigned long long q;
        for (;;) {
          q = ALOAD64(pp);
          if ((unsigned)(q >> 32) == epw) break;
          __builtin_amdgcn_s_sleep(1);
        }
        float pv = __uint_as_float((unsigned)q);
        float p2 = pv + __shfl_xor(pv, 1);
        if ((tid & 1) == 0) hinc[tid >> 1] = p2;
      }
      __syncthreads();
      if (tid < 128) {
        float hn = hb[tid] + hinc[tid];
        hb[tid] = hn;
        hist[((size_t)(t+1)*kB + b_own)*kD + tid] = hn;
      }
      __syncthreads();
    }
  }
}

__global__ void __launch_bounds__(512)
rde_readout(const float* __restrict__ hist, const float* __restrict__ rw,
            const float* __restrict__ rb, float* __restrict__ out) {
  const int t = blockIdx.x, tid = threadIdx.x;
  const int b = tid >> 5, o = tid & 31;
  const float4* hr = (const float4*)(hist + ((size_t)t*kB + b)*kD);
  const float4* wr = (const float4*)(rw + (size_t)o*kD);
  float a = rb[o];
#pragma unroll 8
  for (int q = 0; q < kD/4; ++q) {
    float4 h4 = hr[q], w4 = wr[q];
    a = fmaf(h4.x,w4.x,a); a = fmaf(h4.y,w4.y,a);
    a = fmaf(h4.z,w4.z,a); a = fmaf(h4.w,w4.w,a);
  }
  out[((size_t)b*kT + t)*kO + o] = a;
}

extern "C" void kernel_launch(void* const* d_in, const int* in_sizes, int n_in,
                              void* d_out, int out_size, void* d_ws, size_t ws_size,
                              hipStream_t stream) {
  const float* x0  = (const float*)d_in[0];
  const float* lsg = (const float*)d_in[1];
  const float* iw1 = (const float*)d_in[2];
  const float* ib1 = (const float*)d_in[3];
  const float* iw2 = (const float*)d_in[4];
  const float* ib2 = (const float*)d_in[5];
  const float* iw3 = (const float*)d_in[6];
  const float* ib3 = (const float*)d_in[7];
  const float* fw1 = (const float*)d_in[8];
  const float* fb1 = (const float*)d_in[9];
  const float* fw2 = (const float*)d_in[10];
  const float* fb2 = (const float*)d_in[11];
  const float* fw3 = (const float*)d_in[12];
  const float* fb3 = (const float*)d_in[13];
  const float* rw  = (const float*)d_in[14];
  const float* rb  = (const float*)d_in[15];
  float* out = (float*)d_out;

  float* hist = (float*)d_ws;                                       // 512*16*128 f32
  unsigned long long* z2x   = (unsigned long long*)(hist + (size_t)kT*kB*kD); // [16][256]
  unsigned long long* partx = z2x + (size_t)kB*kH;                  // [16][256]

  hipMemsetAsync(z2x, 0, (size_t)kB*kH*8 * 2, stream);
  hipFuncSetAttribute((const void*)rde_scan,
                      hipFuncAttributeMaxDynamicSharedMemorySize, (int)LDS_BYTES);

  rde_init<<<kB, 256, 0, stream>>>(x0, iw1, ib1, iw2, ib2, iw3, ib3, hist);

  void* args[] = { (void*)&lsg, (void*)&fw1, (void*)&fb1, (void*)&fw2, (void*)&fb2,
                   (void*)&fw3, (void*)&fb3, (void*)&hist, (void*)&z2x, (void*)&partx };
  hipLaunchCooperativeKernel((const void*)rde_scan, dim3(NBLK), dim3(NTHR),
                             args, (unsigned)LDS_BYTES, stream);

  rde_readout<<<kT, 512, 0, stream>>>(hist, rw, rb, out);
}